// Round 1
// baseline (1024.545 us; speedup 1.0000x reference)
//
#include <hip/hip_runtime.h>

typedef unsigned short ushort_t;
typedef unsigned int uint_t;
typedef __attribute__((ext_vector_type(8))) short short8;
typedef __attribute__((ext_vector_type(4))) float floatx4;

// ---------- bf16 helpers ----------
__device__ __forceinline__ ushort_t f2bf(float f){
  uint_t u = __builtin_bit_cast(uint_t, f);
  u += 0x7FFFu + ((u >> 16) & 1u);          // RNE
  return (ushort_t)(u >> 16);
}
__device__ __forceinline__ float bf2f(ushort_t u){
  uint_t x = ((uint_t)u) << 16;
  return __builtin_bit_cast(float, x);
}
__device__ __forceinline__ uint_t packbf2(float a, float b){
  return (uint_t)f2bf(a) | ((uint_t)f2bf(b) << 16);
}

// ---------- elementwise add (float4 granularity) ----------
__global__ __launch_bounds__(256) void add_kernel(const float* __restrict__ a,
    const float* __restrict__ b, float* __restrict__ c, int n4){
  int i = blockIdx.x * 256 + threadIdx.x;
  if (i < n4){
    float4 x = ((const float4*)a)[i];
    float4 y = ((const float4*)b)[i];
    float4 z; z.x=x.x+y.x; z.y=x.y+y.y; z.z=x.z+y.z; z.w=x.w+y.w;
    ((float4*)c)[i] = z;
  }
}

// ---------- add + layernorm (one wave per 256-wide row) ----------
__global__ __launch_bounds__(256) void addln_kernel(const float* __restrict__ X,
    const float* __restrict__ Y, const float* __restrict__ gw,
    const float* __restrict__ bw, float* __restrict__ Out){
  int wave = threadIdx.x >> 6, lane = threadIdx.x & 63;
  long row = (long)blockIdx.x * 4 + wave;
  long base = row * 256 + lane * 4;
  float4 x = *(const float4*)(X + base);
  float4 y = *(const float4*)(Y + base);
  float v0=x.x+y.x, v1=x.y+y.y, v2=x.z+y.z, v3=x.w+y.w;
  float s  = v0+v1+v2+v3;
  float sq = v0*v0+v1*v1+v2*v2+v3*v3;
  #pragma unroll
  for (int off=32; off>0; off>>=1){
    s  += __shfl_xor(s, off);
    sq += __shfl_xor(sq, off);
  }
  float mu  = s * (1.f/256.f);
  float var = sq * (1.f/256.f) - mu*mu;
  float rs  = rsqrtf(var + 1e-5f);
  float4 g4 = *(const float4*)(gw + lane*4);
  float4 b4 = *(const float4*)(bw + lane*4);
  float4 o;
  o.x = (v0-mu)*rs*g4.x + b4.x;
  o.y = (v1-mu)*rs*g4.y + b4.y;
  o.z = (v2-mu)*rs*g4.z + b4.z;
  o.w = (v3-mu)*rs*g4.w + b4.w;
  *(float4*)(Out + base) = o;
}

// ---------- generic bf16-MFMA GEMM:  C[M,N] = A[M,K] @ W[N,K]^T + bias ----------
// 128x128 tile, BK=32, 256 threads (4 waves 2x2, each wave 64x64 via 4x4 16x16 frags)
// LDS layout: row r (64B), 16B slot s stored at s ^ ((r>>1)&3)  -> conflict-free b128 reads.
__device__ __forceinline__ void stage_store(ushort_t* ls, int r, int c4, float4 v){
  int byte = r*64 + ((((c4>>1) ^ ((r>>1)&3)) << 4) | ((c4&1) << 3));
  uint_t u0 = packbf2(v.x, v.y);
  uint_t u1 = packbf2(v.z, v.w);
  uint2 u; u.x = u0; u.y = u1;
  *(uint2*)((char*)ls + byte) = u;
}
__device__ __forceinline__ short8 frag_load(const ushort_t* ls, int r, int g){
  int byte = r*64 + ((g ^ ((r>>1)&3)) << 4);
  return *(const short8*)((const char*)ls + byte);
}

template<bool RELU, bool OUT_BF16>
__global__ __launch_bounds__(256) void gemm_kernel(const float* __restrict__ A,
    const float* __restrict__ W, const float* __restrict__ bias,
    void* __restrict__ Cout, int M, int N, int K){
  __shared__ ushort_t lsA[4096], lsB[4096];
  const int t = threadIdx.x;
  const int lane = t & 63, wave = t >> 6;
  const int wm = wave >> 1, wn = wave & 1;
  const long rowA0 = (long)blockIdx.x * 128;
  const long rowB0 = (long)blockIdx.y * 128;
  floatx4 acc[4][4] = {};
  const int rr = lane & 15, g = lane >> 4;
  for (int k0 = 0; k0 < K; k0 += 32){
    __syncthreads();
    #pragma unroll
    for (int j = 0; j < 4; ++j){
      int i = t + j*256; int r = i >> 3, c4 = i & 7;
      float4 va = *(const float4*)(A + (rowA0 + r)*(long)K + k0 + c4*4);
      stage_store(lsA, r, c4, va);
      float4 vb = *(const float4*)(W + (rowB0 + r)*(long)K + k0 + c4*4);
      stage_store(lsB, r, c4, vb);
    }
    __syncthreads();
    short8 af[4], bfr[4];
    #pragma unroll
    for (int mi=0;mi<4;++mi) af[mi]  = frag_load(lsA, wm*64 + mi*16 + rr, g);
    #pragma unroll
    for (int ni=0;ni<4;++ni) bfr[ni] = frag_load(lsB, wn*64 + ni*16 + rr, g);
    #pragma unroll
    for (int mi=0;mi<4;++mi)
      #pragma unroll
      for (int ni=0;ni<4;++ni)
        acc[mi][ni] = __builtin_amdgcn_mfma_f32_16x16x32_bf16(af[mi], bfr[ni], acc[mi][ni], 0, 0, 0);
  }
  // epilogue: C/D layout col=lane&15, row=(lane>>4)*4+reg  [verified]
  const int cg = lane >> 4;
  #pragma unroll
  for (int ni=0;ni<4;++ni){
    long n = rowB0 + wn*64 + ni*16 + (lane & 15);
    float bv = bias[n];
    #pragma unroll
    for (int mi=0;mi<4;++mi){
      long m = rowA0 + wm*64 + mi*16 + cg*4;
      #pragma unroll
      for (int r2=0;r2<4;++r2){
        float v = acc[mi][ni][r2] + bv;
        if (RELU) v = fmaxf(v, 0.f);
        if (OUT_BF16) ((ushort_t*)Cout)[(m+r2)*N + n] = f2bf(v);
        else          ((float*)Cout)[(m+r2)*N + n] = v;
      }
    }
  }
}

// ---------- MHA attention: lane = q-row, uniform K/V row broadcast ----------
// QK: (8,1024,512) [q cols 0-255 (h*32+d), k cols 256-511]; V: (8,1024,256)
// scores small -> softmax without max subtraction (exact ratio preserved).
__global__ __launch_bounds__(256) void attn_kernel(const float* __restrict__ QK,
    const float* __restrict__ V, float* __restrict__ O){
  int bh = blockIdx.y; int b = bh >> 3, h = bh & 7;
  int wave = threadIdx.x >> 6, lane = threadIdx.x & 63;
  int row = blockIdx.x*256 + wave*64 + lane;
  const float* qptr = QK + ((long)b*1024 + row)*512 + h*32;
  float4 q4[8];
  #pragma unroll
  for (int j=0;j<8;++j) q4[j] = *(const float4*)(qptr + j*4);
  float4 o4[8];
  #pragma unroll
  for (int j=0;j<8;++j){ o4[j].x=0.f; o4[j].y=0.f; o4[j].z=0.f; o4[j].w=0.f; }
  float ssum = 0.f;
  const float csc = 0.25506332f;  // log2(e)/sqrt(32)
  const float* kbase = QK + (long)b*1024*512 + 256 + h*32;
  const float* vbase = V  + (long)b*1024*256 + h*32;
  for (int k=0;k<1024;++k){
    const float4* kp = (const float4*)(kbase + (long)k*512);
    const float4* vp = (const float4*)(vbase + (long)k*256);
    float s0=0.f,s1=0.f,s2=0.f,s3=0.f;
    #pragma unroll
    for (int j=0;j<8;++j){
      float4 kv = kp[j];
      s0 = fmaf(q4[j].x, kv.x, s0);
      s1 = fmaf(q4[j].y, kv.y, s1);
      s2 = fmaf(q4[j].z, kv.z, s2);
      s3 = fmaf(q4[j].w, kv.w, s3);
    }
    float sc = (s0+s1)+(s2+s3);
    float p = exp2f(sc * csc);
    ssum += p;
    #pragma unroll
    for (int j=0;j<8;++j){
      float4 vv = vp[j];
      o4[j].x = fmaf(p, vv.x, o4[j].x);
      o4[j].y = fmaf(p, vv.y, o4[j].y);
      o4[j].z = fmaf(p, vv.z, o4[j].z);
      o4[j].w = fmaf(p, vv.w, o4[j].w);
    }
  }
  float inv = 1.f/ssum;
  float* op = O + ((long)b*1024 + row)*256 + h*32;
  #pragma unroll
  for (int j=0;j<8;++j){
    float4 w; w.x=o4[j].x*inv; w.y=o4[j].y*inv; w.z=o4[j].z*inv; w.w=o4[j].w*inv;
    *(float4*)(op + j*4) = w;
  }
}

// ---------- multi-scale deformable attention sampling ----------
// value bf16 (B,21760,8,32); off (B,LQ,256); awl (B,LQ,128); refp (B,LQ,4,2)
__global__ __launch_bounds__(256) void deform_kernel(const ushort_t* __restrict__ val,
    const float* __restrict__ offs, const float* __restrict__ awl,
    const float* __restrict__ refp, float* __restrict__ Out){
  int bq = blockIdx.x; int b = bq >> 10;
  int t = threadIdx.x; int h = t >> 5, d = t & 31;
  __shared__ float s_off[256], s_aw[128], s_ref[8];
  s_off[t] = offs[(long)bq*256 + t];
  if (t < 128) s_aw[t] = awl[(long)bq*128 + t];
  if (t < 8)   s_ref[t] = refp[(long)bq*8 + t];
  __syncthreads();
  // softmax over the 16 (level,point) logits of this head
  float mx = -1e30f;
  #pragma unroll
  for (int i=0;i<16;++i) mx = fmaxf(mx, s_aw[h*16+i]);
  float p[16], sum = 0.f;
  #pragma unroll
  for (int i=0;i<16;++i){ p[i] = expf(s_aw[h*16+i] - mx); sum += p[i]; }
  float inv = 1.f/sum;
  const long vb = (long)b*21760*256 + h*32 + d;
  const int Ws[4] = {128,64,32,16};
  const int Hs[4] = {128,64,32,16};
  const int St[4] = {0,16384,20480,21504};
  float acc = 0.f;
  #pragma unroll
  for (int l=0;l<4;++l){
    const int Wl = Ws[l], Hl = Hs[l], st = St[l];
    float rx = s_ref[2*l], ry = s_ref[2*l+1];
    #pragma unroll
    for (int pp=0;pp<4;++pp){
      float ox = s_off[h*32 + l*8 + pp*2];
      float oy = s_off[h*32 + l*8 + pp*2 + 1];
      float x = rx*(float)Wl + ox - 0.5f;
      float y = ry*(float)Hl + oy - 0.5f;
      float xf = floorf(x), yf = floorf(y);
      int x0 = (int)xf, y0 = (int)yf;
      float tx = x - xf, ty = y - yf;
      float w00 = (1.f-tx)*(1.f-ty), w10 = tx*(1.f-ty);
      float w01 = (1.f-tx)*ty,       w11 = tx*ty;
      float sample = 0.f;
      if (x0 >= 0   && x0   < Wl && y0 >= 0   && y0   < Hl)
        sample += w00 * bf2f(val[vb + (long)(st + y0*Wl + x0)*256]);
      if (x0+1 >= 0 && x0+1 < Wl && y0 >= 0   && y0   < Hl)
        sample += w10 * bf2f(val[vb + (long)(st + y0*Wl + x0+1)*256]);
      if (x0 >= 0   && x0   < Wl && y0+1 >= 0 && y0+1 < Hl)
        sample += w01 * bf2f(val[vb + (long)(st + (y0+1)*Wl + x0)*256]);
      if (x0+1 >= 0 && x0+1 < Wl && y0+1 >= 0 && y0+1 < Hl)
        sample += w11 * bf2f(val[vb + (long)(st + (y0+1)*Wl + x0+1)*256]);
      acc += p[l*4+pp] * sample;
    }
  }
  Out[(long)bq*256 + t] = acc * inv;
}

// ---------------- host launcher ----------------
extern "C" void kernel_launch(void* const* d_in, const int* in_sizes, int n_in,
                              void* d_out, int out_size, void* d_ws, size_t ws_size,
                              hipStream_t stream){
  (void)in_sizes; (void)n_in; (void)out_size; (void)ws_size;
  const float* tgt   = (const float*)d_in[0];
  const float* qpos  = (const float*)d_in[1];
  const float* refp  = (const float*)d_in[2];
  const float* src   = (const float*)d_in[3];
  const float* w_in  = (const float*)d_in[4];
  const float* b_in  = (const float*)d_in[5];
  const float* w_out = (const float*)d_in[6];
  const float* b_out = (const float*)d_in[7];
  const float* ln1g  = (const float*)d_in[8];
  const float* ln1b  = (const float*)d_in[9];
  const float* ln2g  = (const float*)d_in[10];
  const float* ln2b  = (const float*)d_in[11];
  const float* ln3g  = (const float*)d_in[12];
  const float* ln3b  = (const float*)d_in[13];
  const float* w_val = (const float*)d_in[14];
  const float* b_val = (const float*)d_in[15];
  const float* w_off = (const float*)d_in[16];
  const float* b_off = (const float*)d_in[17];
  const float* w_attw= (const float*)d_in[18];
  const float* b_attw= (const float*)d_in[19];
  const float* w_oc  = (const float*)d_in[20];
  const float* b_oc  = (const float*)d_in[21];
  const float* w1    = (const float*)d_in[22];
  const float* b1    = (const float*)d_in[23];
  const float* w2    = (const float*)d_in[24];
  const float* b2    = (const float*)d_in[25];

  float* ws = (float*)d_ws;
  float* bufA   = ws;                    // 2M floats (qk, later query)
  float* bufQK  = ws + 2097152;          // 4M floats (q|k proj)
  float* bufOff = ws + 2097152;          // reuse of bufQK region (after attn)
  float* bufAW  = ws + 4194304;          // reuse of bufQK region
  float* bufV   = ws + 6291456;          // 2M
  float* bufO   = ws + 8388608;          // 2M
  float* bufT2  = ws + 10485760;         // 2M
  float* bufTg1 = ws + 12582912;         // 2M
  float* bufTg2 = ws + 14680064;         // 2M
  ushort_t* bufVal = (ushort_t*)(ws + 16777216);  // 44.56M bf16 (89MB)
  float* bufH   = ws + 16777216;         // reuse bufVal region (FFN hidden, 32MB)
  float* outF   = (float*)d_out;

  dim3 B256(256);
  // 1. qk = tgt + query_pos
  add_kernel<<<dim3(2048), B256, 0, stream>>>(tgt, qpos, bufA, 524288);
  // 2. q|k projection (w_in rows 0..511)
  gemm_kernel<false,false><<<dim3(64,4), B256, 0, stream>>>(bufA, w_in, b_in, bufQK, 8192, 512, 256);
  // 3. v projection (w_in rows 512..767, input = tgt)
  gemm_kernel<false,false><<<dim3(64,2), B256, 0, stream>>>(tgt, w_in + 512*256, b_in + 512, bufV, 8192, 256, 256);
  // 4. attention
  attn_kernel<<<dim3(4,64), B256, 0, stream>>>(bufQK, bufV, bufO);
  // 5. output projection
  gemm_kernel<false,false><<<dim3(64,2), B256, 0, stream>>>(bufO, w_out, b_out, bufT2, 8192, 256, 256);
  // 6. tgt1 = LN2(tgt + t2)
  addln_kernel<<<dim3(2048), B256, 0, stream>>>(tgt, bufT2, ln2g, ln2b, bufTg1);
  // 7. query = tgt1 + query_pos
  add_kernel<<<dim3(2048), B256, 0, stream>>>(bufTg1, qpos, bufA, 524288);
  // 8. value projection (bf16 out)
  gemm_kernel<false,true><<<dim3(1360,2), B256, 0, stream>>>(src, w_val, b_val, bufVal, 174080, 256, 256);
  // 9. sampling offsets
  gemm_kernel<false,false><<<dim3(64,2), B256, 0, stream>>>(bufA, w_off, b_off, bufOff, 8192, 256, 256);
  // 10. attention-weight logits
  gemm_kernel<false,false><<<dim3(64,1), B256, 0, stream>>>(bufA, w_attw, b_attw, bufAW, 8192, 128, 256);
  // 11. deformable sampling
  deform_kernel<<<dim3(8192), B256, 0, stream>>>(bufVal, bufOff, bufAW, refp, bufO);
  // 12. output-context projection
  gemm_kernel<false,false><<<dim3(64,2), B256, 0, stream>>>(bufO, w_oc, b_oc, bufT2, 8192, 256, 256);
  // 13. tgt2 = LN1(tgt1 + ca)
  addln_kernel<<<dim3(2048), B256, 0, stream>>>(bufTg1, bufT2, ln1g, ln1b, bufTg2);
  // 14. FFN up + relu
  gemm_kernel<true,false><<<dim3(64,8), B256, 0, stream>>>(bufTg2, w1, b1, bufH, 8192, 1024, 256);
  // 15. FFN down
  gemm_kernel<false,false><<<dim3(64,2), B256, 0, stream>>>(bufH, w2, b2, bufT2, 8192, 256, 1024);
  // 16. out = LN3(tgt2 + t2)
  addln_kernel<<<dim3(2048), B256, 0, stream>>>(bufTg2, bufT2, ln3g, ln3b, outF);
}

// Round 2
// 443.561 us; speedup vs baseline: 2.3098x; 2.3098x over previous
//
#include <hip/hip_runtime.h>

typedef unsigned short ushort_t;
typedef unsigned int uint_t;
typedef __attribute__((ext_vector_type(8))) short short8;
typedef __attribute__((ext_vector_type(4))) float floatx4;

// ---------- bf16 helpers ----------
__device__ __forceinline__ ushort_t f2bf(float f){
  uint_t u = __builtin_bit_cast(uint_t, f);
  u += 0x7FFFu + ((u >> 16) & 1u);          // RNE
  return (ushort_t)(u >> 16);
}
__device__ __forceinline__ float bf2f(ushort_t u){
  uint_t x = ((uint_t)u) << 16;
  return __builtin_bit_cast(float, x);
}
__device__ __forceinline__ uint_t packbf2(float a, float b){
  return (uint_t)f2bf(a) | ((uint_t)f2bf(b) << 16);
}

// ---------- elementwise add (float4 granularity) ----------
__global__ __launch_bounds__(256) void add_kernel(const float* __restrict__ a,
    const float* __restrict__ b, float* __restrict__ c, int n4){
  int i = blockIdx.x * 256 + threadIdx.x;
  if (i < n4){
    float4 x = ((const float4*)a)[i];
    float4 y = ((const float4*)b)[i];
    float4 z; z.x=x.x+y.x; z.y=x.y+y.y; z.z=x.z+y.z; z.w=x.w+y.w;
    ((float4*)c)[i] = z;
  }
}

// ---------- add + layernorm (one wave per 256-wide row) ----------
__global__ __launch_bounds__(256) void addln_kernel(const float* __restrict__ X,
    const float* __restrict__ Y, const float* __restrict__ gw,
    const float* __restrict__ bw, float* __restrict__ Out){
  int wave = threadIdx.x >> 6, lane = threadIdx.x & 63;
  long row = (long)blockIdx.x * 4 + wave;
  long base = row * 256 + lane * 4;
  float4 x = *(const float4*)(X + base);
  float4 y = *(const float4*)(Y + base);
  float v0=x.x+y.x, v1=x.y+y.y, v2=x.z+y.z, v3=x.w+y.w;
  float s  = v0+v1+v2+v3;
  float sq = v0*v0+v1*v1+v2*v2+v3*v3;
  #pragma unroll
  for (int off=32; off>0; off>>=1){
    s  += __shfl_xor(s, off);
    sq += __shfl_xor(sq, off);
  }
  float mu  = s * (1.f/256.f);
  float var = sq * (1.f/256.f) - mu*mu;
  float rs  = rsqrtf(var + 1e-5f);
  float4 g4 = *(const float4*)(gw + lane*4);
  float4 b4 = *(const float4*)(bw + lane*4);
  float4 o;
  o.x = (v0-mu)*rs*g4.x + b4.x;
  o.y = (v1-mu)*rs*g4.y + b4.y;
  o.z = (v2-mu)*rs*g4.z + b4.z;
  o.w = (v3-mu)*rs*g4.w + b4.w;
  *(float4*)(Out + base) = o;
}

// ---------- shared LDS tile helpers (64B rows, xor-swizzled 16B slots) ----------
__device__ __forceinline__ void stage_store(ushort_t* ls, int r, int c4, float4 v){
  int byte = r*64 + ((((c4>>1) ^ ((r>>1)&3)) << 4) | ((c4&1) << 3));
  uint2 u; u.x = packbf2(v.x, v.y); u.y = packbf2(v.z, v.w);
  *(uint2*)((char*)ls + byte) = u;
}
__device__ __forceinline__ short8 frag_load(const ushort_t* ls, int r, int g){
  int byte = r*64 + ((g ^ ((r>>1)&3)) << 4);
  return *(const short8*)((const char*)ls + byte);
}

// ---------- generic bf16-MFMA GEMM:  C[M,N] = A[M,K] @ W[N,K]^T + bias ----------
template<bool RELU, bool OUT_BF16>
__global__ __launch_bounds__(256) void gemm_kernel(const float* __restrict__ A,
    const float* __restrict__ W, const float* __restrict__ bias,
    void* __restrict__ Cout, int M, int N, int K){
  __shared__ ushort_t lsA[4096], lsB[4096];
  const int t = threadIdx.x;
  const int lane = t & 63, wave = t >> 6;
  const int wm = wave >> 1, wn = wave & 1;
  const long rowA0 = (long)blockIdx.x * 128;
  const long rowB0 = (long)blockIdx.y * 128;
  floatx4 acc[4][4] = {};
  const int rr = lane & 15, g = lane >> 4;
  for (int k0 = 0; k0 < K; k0 += 32){
    __syncthreads();
    #pragma unroll
    for (int j = 0; j < 4; ++j){
      int i = t + j*256; int r = i >> 3, c4 = i & 7;
      float4 va = *(const float4*)(A + (rowA0 + r)*(long)K + k0 + c4*4);
      stage_store(lsA, r, c4, va);
      float4 vb = *(const float4*)(W + (rowB0 + r)*(long)K + k0 + c4*4);
      stage_store(lsB, r, c4, vb);
    }
    __syncthreads();
    short8 af[4], bfr[4];
    #pragma unroll
    for (int mi=0;mi<4;++mi) af[mi]  = frag_load(lsA, wm*64 + mi*16 + rr, g);
    #pragma unroll
    for (int ni=0;ni<4;++ni) bfr[ni] = frag_load(lsB, wn*64 + ni*16 + rr, g);
    #pragma unroll
    for (int mi=0;mi<4;++mi)
      #pragma unroll
      for (int ni=0;ni<4;++ni)
        acc[mi][ni] = __builtin_amdgcn_mfma_f32_16x16x32_bf16(af[mi], bfr[ni], acc[mi][ni], 0, 0, 0);
  }
  const int cg = lane >> 4;
  #pragma unroll
  for (int ni=0;ni<4;++ni){
    long n = rowB0 + wn*64 + ni*16 + (lane & 15);
    float bv = bias[n];
    #pragma unroll
    for (int mi=0;mi<4;++mi){
      long m = rowA0 + wm*64 + mi*16 + cg*4;
      #pragma unroll
      for (int r2=0;r2<4;++r2){
        float v = acc[mi][ni][r2] + bv;
        if (RELU) v = fmaxf(v, 0.f);
        if (OUT_BF16) ((ushort_t*)Cout)[(m+r2)*N + n] = f2bf(v);
        else          ((float*)Cout)[(m+r2)*N + n] = v;
      }
    }
  }
}

// ---------- MFMA flash attention ----------
// QK: (8,1024,512) [q cols 0-255 (h*32+dh), k cols 256-511]; V: (8,1024,256)
// Per block: one (b,h), 128 q rows (wave w owns q rows w*32..w*32+31).
// S^T = mfma(K, Q)  -> lane holds 4 consecutive k at fixed q -> packed b64 P-writes.
// O^T = mfma(V^T, P) with P as [q][k] (B-operand layout), V^T staged transposed.
// Scores are tiny (std ~0.1) -> softmax without max subtraction is safe.
__global__ __launch_bounds__(256) void attn_mfma_kernel(const float* __restrict__ QK,
    const float* __restrict__ V, float* __restrict__ O){
  __shared__ ushort_t lsQ[4096];   // [128 q][32 dh]
  __shared__ ushort_t lsK[1024];   // [32 k][32 dh]
  __shared__ ushort_t lsVT[1024];  // [32 d][32 k]
  __shared__ ushort_t lsP[4096];   // [128 q][32 k]
  const int bh = blockIdx.y, b = bh >> 3, h = bh & 7;
  const int qt0 = blockIdx.x * 128;
  const int t = threadIdx.x, lane = t & 63, w = t >> 6;
  const int rr = lane & 15, g = lane >> 4;
  const float csc = 0.25506332f;   // log2(e)/sqrt(32)

  // stage Q tile (128 x 32)
  const float* qbase = QK + ((long)b*1024 + qt0)*512 + h*32;
  #pragma unroll
  for (int j=0;j<4;++j){
    int i = t + j*256; int r = i>>3, c4 = i&7;
    float4 v = *(const float4*)(qbase + (long)r*512 + c4*4);
    stage_store(lsQ, r, c4, v);
  }
  __syncthreads();
  short8 bq[2];
  bq[0] = frag_load(lsQ, w*32 + rr, g);
  bq[1] = frag_load(lsQ, w*32 + 16 + rr, g);

  floatx4 accO[2][2] = {};
  float rsum[2] = {0.f, 0.f};
  const float* kbase = QK + (long)b*1024*512 + 256 + h*32;
  const float* vbase = V  + (long)b*1024*256 + h*32;

  for (int kt = 0; kt < 1024; kt += 32){
    __syncthreads();
    { // stage K tile (32 x 32), natural layout
      int r = t >> 3, c4 = t & 7;
      float4 v = *(const float4*)(kbase + (long)(kt + r)*512 + c4*4);
      stage_store(lsK, r, c4, v);
    }
    { // stage V tile transposed -> lsVT[d][k]
      int kk = t >> 3, d4 = t & 7;
      float4 vv = *(const float4*)(vbase + (long)(kt + kk)*256 + d4*4);
      float vals[4] = {vv.x, vv.y, vv.z, vv.w};
      #pragma unroll
      for (int j=0;j<4;++j){
        int d = d4*4 + j;
        int cb = kk*2;
        int byte = d*64 + ((((cb>>4) ^ ((d>>1)&3)) << 4) | (cb & 15));
        *(ushort_t*)((char*)lsVT + byte) = f2bf(vals[j]);
      }
    }
    __syncthreads();
    // S^T = K @ Q^T  (m = k-row, n = q)
    floatx4 accS[2][2] = {};
    short8 ak0 = frag_load(lsK, rr, g);
    short8 ak1 = frag_load(lsK, 16 + rr, g);
    accS[0][0] = __builtin_amdgcn_mfma_f32_16x16x32_bf16(ak0, bq[0], accS[0][0], 0,0,0);
    accS[0][1] = __builtin_amdgcn_mfma_f32_16x16x32_bf16(ak0, bq[1], accS[0][1], 0,0,0);
    accS[1][0] = __builtin_amdgcn_mfma_f32_16x16x32_bf16(ak1, bq[0], accS[1][0], 0,0,0);
    accS[1][1] = __builtin_amdgcn_mfma_f32_16x16x32_bf16(ak1, bq[1], accS[1][1], 0,0,0);
    // exp2 -> P (bf16, packed b64 writes into wave-private lsP rows), row-sum accum
    #pragma unroll
    for (int mi=0;mi<2;++mi){
      #pragma unroll
      for (int ni=0;ni<2;++ni){
        float p0 = exp2f(accS[mi][ni][0]*csc);
        float p1 = exp2f(accS[mi][ni][1]*csc);
        float p2 = exp2f(accS[mi][ni][2]*csc);
        float p3 = exp2f(accS[mi][ni][3]*csc);
        rsum[ni] += (p0+p1)+(p2+p3);
        int q   = w*32 + ni*16 + rr;
        int k0b = (mi*16 + g*4)*2;
        int byte = q*64 + ((((k0b>>4) ^ ((q>>1)&3)) << 4) | (k0b & 15));
        uint2 u; u.x = packbf2(p0,p1); u.y = packbf2(p2,p3);
        *(uint2*)((char*)lsP + byte) = u;
      }
    }
    // O^T += V^T @ P^T  (m = d, n = q); wave reads only its own lsP rows
    short8 av0 = frag_load(lsVT, rr, g);
    short8 av1 = frag_load(lsVT, 16 + rr, g);
    short8 bp0 = frag_load(lsP, w*32 + rr, g);
    short8 bp1 = frag_load(lsP, w*32 + 16 + rr, g);
    accO[0][0] = __builtin_amdgcn_mfma_f32_16x16x32_bf16(av0, bp0, accO[0][0], 0,0,0);
    accO[0][1] = __builtin_amdgcn_mfma_f32_16x16x32_bf16(av0, bp1, accO[0][1], 0,0,0);
    accO[1][0] = __builtin_amdgcn_mfma_f32_16x16x32_bf16(av1, bp0, accO[1][0], 0,0,0);
    accO[1][1] = __builtin_amdgcn_mfma_f32_16x16x32_bf16(av1, bp1, accO[1][1], 0,0,0);
  }
  // finalize: reduce row-sums across the four g-groups, normalize, store
  #pragma unroll
  for (int ni=0;ni<2;++ni){
    rsum[ni] += __shfl_xor(rsum[ni], 16);
    rsum[ni] += __shfl_xor(rsum[ni], 32);
    float inv = 1.f / rsum[ni];
    int q = qt0 + w*32 + ni*16 + rr;
    float* op = O + ((long)b*1024 + q)*256 + h*32;
    #pragma unroll
    for (int mi=0;mi<2;++mi){
      #pragma unroll
      for (int r2=0;r2<4;++r2){
        int d = mi*16 + g*4 + r2;
        op[d] = accO[mi][ni][r2] * inv;
      }
    }
  }
}

// ---------- multi-scale deformable attention sampling ----------
__global__ __launch_bounds__(256) void deform_kernel(const ushort_t* __restrict__ val,
    const float* __restrict__ offs, const float* __restrict__ awl,
    const float* __restrict__ refp, float* __restrict__ Out){
  int bq = blockIdx.x; int b = bq >> 10;
  int t = threadIdx.x; int h = t >> 5, d = t & 31;
  __shared__ float s_off[256], s_aw[128], s_ref[8];
  s_off[t] = offs[(long)bq*256 + t];
  if (t < 128) s_aw[t] = awl[(long)bq*128 + t];
  if (t < 8)   s_ref[t] = refp[(long)bq*8 + t];
  __syncthreads();
  float mx = -1e30f;
  #pragma unroll
  for (int i=0;i<16;++i) mx = fmaxf(mx, s_aw[h*16+i]);
  float p[16], sum = 0.f;
  #pragma unroll
  for (int i=0;i<16;++i){ p[i] = expf(s_aw[h*16+i] - mx); sum += p[i]; }
  float inv = 1.f/sum;
  const long vb = (long)b*21760*256 + h*32 + d;
  const int Ws[4] = {128,64,32,16};
  const int Hs[4] = {128,64,32,16};
  const int St[4] = {0,16384,20480,21504};
  float acc = 0.f;
  #pragma unroll
  for (int l=0;l<4;++l){
    const int Wl = Ws[l], Hl = Hs[l], st = St[l];
    float rx = s_ref[2*l], ry = s_ref[2*l+1];
    #pragma unroll
    for (int pp=0;pp<4;++pp){
      float ox = s_off[h*32 + l*8 + pp*2];
      float oy = s_off[h*32 + l*8 + pp*2 + 1];
      float x = rx*(float)Wl + ox - 0.5f;
      float y = ry*(float)Hl + oy - 0.5f;
      float xf = floorf(x), yf = floorf(y);
      int x0 = (int)xf, y0 = (int)yf;
      float tx = x - xf, ty = y - yf;
      float w00 = (1.f-tx)*(1.f-ty), w10 = tx*(1.f-ty);
      float w01 = (1.f-tx)*ty,       w11 = tx*ty;
      float sample = 0.f;
      if (x0 >= 0   && x0   < Wl && y0 >= 0   && y0   < Hl)
        sample += w00 * bf2f(val[vb + (long)(st + y0*Wl + x0)*256]);
      if (x0+1 >= 0 && x0+1 < Wl && y0 >= 0   && y0   < Hl)
        sample += w10 * bf2f(val[vb + (long)(st + y0*Wl + x0+1)*256]);
      if (x0 >= 0   && x0   < Wl && y0+1 >= 0 && y0+1 < Hl)
        sample += w01 * bf2f(val[vb + (long)(st + (y0+1)*Wl + x0)*256]);
      if (x0+1 >= 0 && x0+1 < Wl && y0+1 >= 0 && y0+1 < Hl)
        sample += w11 * bf2f(val[vb + (long)(st + (y0+1)*Wl + x0+1)*256]);
      acc += p[l*4+pp] * sample;
    }
  }
  Out[(long)bq*256 + t] = acc * inv;
}

// ---------------- host launcher ----------------
extern "C" void kernel_launch(void* const* d_in, const int* in_sizes, int n_in,
                              void* d_out, int out_size, void* d_ws, size_t ws_size,
                              hipStream_t stream){
  (void)in_sizes; (void)n_in; (void)out_size; (void)ws_size;
  const float* tgt   = (const float*)d_in[0];
  const float* qpos  = (const float*)d_in[1];
  const float* refp  = (const float*)d_in[2];
  const float* src   = (const float*)d_in[3];
  const float* w_in  = (const float*)d_in[4];
  const float* b_in  = (const float*)d_in[5];
  const float* w_out = (const float*)d_in[6];
  const float* b_out = (const float*)d_in[7];
  const float* ln1g  = (const float*)d_in[8];
  const float* ln1b  = (const float*)d_in[9];
  const float* ln2g  = (const float*)d_in[10];
  const float* ln2b  = (const float*)d_in[11];
  const float* ln3g  = (const float*)d_in[12];
  const float* ln3b  = (const float*)d_in[13];
  const float* w_val = (const float*)d_in[14];
  const float* b_val = (const float*)d_in[15];
  const float* w_off = (const float*)d_in[16];
  const float* b_off = (const float*)d_in[17];
  const float* w_attw= (const float*)d_in[18];
  const float* b_attw= (const float*)d_in[19];
  const float* w_oc  = (const float*)d_in[20];
  const float* b_oc  = (const float*)d_in[21];
  const float* w1    = (const float*)d_in[22];
  const float* b1    = (const float*)d_in[23];
  const float* w2    = (const float*)d_in[24];
  const float* b2    = (const float*)d_in[25];

  float* ws = (float*)d_ws;
  float* bufA   = ws;                    // 2M floats (qk, later query)
  float* bufQK  = ws + 2097152;          // 4M floats (q|k proj)
  float* bufOff = ws + 2097152;          // reuse of bufQK region (after attn)
  float* bufAW  = ws + 4194304;          // reuse of bufQK region
  float* bufV   = ws + 6291456;          // 2M
  float* bufO   = ws + 8388608;          // 2M
  float* bufT2  = ws + 10485760;         // 2M
  float* bufTg1 = ws + 12582912;         // 2M
  float* bufTg2 = ws + 14680064;         // 2M
  ushort_t* bufVal = (ushort_t*)(ws + 16777216);  // 44.56M bf16 (89MB)
  float* bufH   = ws + 16777216;         // reuse bufVal region (FFN hidden, 32MB)
  float* outF   = (float*)d_out;

  dim3 B256(256);
  // 1. qk = tgt + query_pos
  add_kernel<<<dim3(2048), B256, 0, stream>>>(tgt, qpos, bufA, 524288);
  // 2. q|k projection (w_in rows 0..511)
  gemm_kernel<false,false><<<dim3(64,4), B256, 0, stream>>>(bufA, w_in, b_in, bufQK, 8192, 512, 256);
  // 3. v projection (w_in rows 512..767, input = tgt)
  gemm_kernel<false,false><<<dim3(64,2), B256, 0, stream>>>(tgt, w_in + 512*256, b_in + 512, bufV, 8192, 256, 256);
  // 4. attention (MFMA flash)
  attn_mfma_kernel<<<dim3(8,64), B256, 0, stream>>>(bufQK, bufV, bufO);
  // 5. output projection
  gemm_kernel<false,false><<<dim3(64,2), B256, 0, stream>>>(bufO, w_out, b_out, bufT2, 8192, 256, 256);
  // 6. tgt1 = LN2(tgt + t2)
  addln_kernel<<<dim3(2048), B256, 0, stream>>>(tgt, bufT2, ln2g, ln2b, bufTg1);
  // 7. query = tgt1 + query_pos
  add_kernel<<<dim3(2048), B256, 0, stream>>>(bufTg1, qpos, bufA, 524288);
  // 8. value projection (bf16 out)
  gemm_kernel<false,true><<<dim3(1360,2), B256, 0, stream>>>(src, w_val, b_val, bufVal, 174080, 256, 256);
  // 9. sampling offsets
  gemm_kernel<false,false><<<dim3(64,2), B256, 0, stream>>>(bufA, w_off, b_off, bufOff, 8192, 256, 256);
  // 10. attention-weight logits
  gemm_kernel<false,false><<<dim3(64,1), B256, 0, stream>>>(bufA, w_attw, b_attw, bufAW, 8192, 128, 256);
  // 11. deformable sampling
  deform_kernel<<<dim3(8192), B256, 0, stream>>>(bufVal, bufOff, bufAW, refp, bufO);
  // 12. output-context projection
  gemm_kernel<false,false><<<dim3(64,2), B256, 0, stream>>>(bufO, w_oc, b_oc, bufT2, 8192, 256, 256);
  // 13. tgt2 = LN1(tgt1 + ca)
  addln_kernel<<<dim3(2048), B256, 0, stream>>>(bufTg1, bufT2, ln1g, ln1b, bufTg2);
  // 14. FFN up + relu
  gemm_kernel<true,false><<<dim3(64,8), B256, 0, stream>>>(bufTg2, w1, b1, bufH, 8192, 1024, 256);
  // 15. FFN down
  gemm_kernel<false,false><<<dim3(64,2), B256, 0, stream>>>(bufH, w2, b2, bufT2, 8192, 256, 1024);
  // 16. out = LN3(tgt2 + t2)
  addln_kernel<<<dim3(2048), B256, 0, stream>>>(bufTg2, bufT2, ln3g, ln3b, outF);
}

// Round 3
// 425.071 us; speedup vs baseline: 2.4103x; 1.0435x over previous
//
#include <hip/hip_runtime.h>

typedef unsigned short ushort_t;
typedef unsigned int uint_t;
typedef __attribute__((ext_vector_type(8))) short short8;
typedef __attribute__((ext_vector_type(4))) float floatx4;

// ---------- bf16 helpers ----------
__device__ __forceinline__ ushort_t f2bf(float f){
  uint_t u = __builtin_bit_cast(uint_t, f);
  u += 0x7FFFu + ((u >> 16) & 1u);          // RNE
  return (ushort_t)(u >> 16);
}
__device__ __forceinline__ float bf2f(ushort_t u){
  uint_t x = ((uint_t)u) << 16;
  return __builtin_bit_cast(float, x);
}
__device__ __forceinline__ uint_t packbf2(float a, float b){
  return (uint_t)f2bf(a) | ((uint_t)f2bf(b) << 16);
}

// ---------- add + layernorm (one wave per 256-wide row) ----------
__global__ __launch_bounds__(256) void addln_kernel(const float* __restrict__ X,
    const float* __restrict__ Y, const float* __restrict__ gw,
    const float* __restrict__ bw, float* __restrict__ Out){
  int wave = threadIdx.x >> 6, lane = threadIdx.x & 63;
  long row = (long)blockIdx.x * 4 + wave;
  long base = row * 256 + lane * 4;
  float4 x = *(const float4*)(X + base);
  float4 y = *(const float4*)(Y + base);
  float v0=x.x+y.x, v1=x.y+y.y, v2=x.z+y.z, v3=x.w+y.w;
  float s  = v0+v1+v2+v3;
  float sq = v0*v0+v1*v1+v2*v2+v3*v3;
  #pragma unroll
  for (int off=32; off>0; off>>=1){
    s  += __shfl_xor(s, off);
    sq += __shfl_xor(sq, off);
  }
  float mu  = s * (1.f/256.f);
  float var = sq * (1.f/256.f) - mu*mu;
  float rs  = rsqrtf(var + 1e-5f);
  float4 g4 = *(const float4*)(gw + lane*4);
  float4 b4 = *(const float4*)(bw + lane*4);
  float4 o;
  o.x = (v0-mu)*rs*g4.x + b4.x;
  o.y = (v1-mu)*rs*g4.y + b4.y;
  o.z = (v2-mu)*rs*g4.z + b4.z;
  o.w = (v3-mu)*rs*g4.w + b4.w;
  *(float4*)(Out + base) = o;
}

// ---------- shared LDS tile helpers (64B rows, xor-swizzled 16B slots) ----------
__device__ __forceinline__ void stage_store(ushort_t* ls, int r, int c4, float4 v){
  int byte = r*64 + ((((c4>>1) ^ ((r>>1)&3)) << 4) | ((c4&1) << 3));
  uint2 u; u.x = packbf2(v.x, v.y); u.y = packbf2(v.z, v.w);
  *(uint2*)((char*)ls + byte) = u;
}
__device__ __forceinline__ short8 frag_load(const ushort_t* ls, int r, int g){
  int byte = r*64 + ((g ^ ((r>>1)&3)) << 4);
  return *(const short8*)((const char*)ls + byte);
}

// ---------- generic bf16-MFMA GEMM:  C[M,N] = A[M,K] @ W[N,K]^T + bias ----------
// 128x128 tile, BK=32, 4 waves 2x2. Register-prefetch pipeline: tile k+1 is
// loaded into VGPRs right after the LDS-ready barrier, so HBM latency hides
// under the MFMA of tile k (latency-bound regime fix, T14).
// ADD2: stage (A + A2) -- fuses the residual/query_pos adds into staging.
template<bool RELU, bool OUT_BF16, bool ADD2>
__global__ __launch_bounds__(256) void gemm_kernel(const float* __restrict__ A,
    const float* __restrict__ A2, const float* __restrict__ W,
    const float* __restrict__ bias, void* __restrict__ Cout,
    int M, int N, int K){
  __shared__ ushort_t lsA[4096], lsB[4096];
  const int t = threadIdx.x;
  const int lane = t & 63, wave = t >> 6;
  const int wm = wave >> 1, wn = wave & 1;
  const long rowA0 = (long)blockIdx.x * 128;
  const long rowB0 = (long)blockIdx.y * 128;
  floatx4 acc[4][4] = {};
  const int rr = lane & 15, g = lane >> 4;
  const int rA = t >> 3, c4 = t & 7;
  const float* Ap = A + (rowA0 + rA)*(long)K + c4*4;
  const float* A2p = ADD2 ? (A2 + (rowA0 + rA)*(long)K + c4*4) : nullptr;
  const float* Wp = W + (rowB0 + rA)*(long)K + c4*4;

  float4 pa[4], pb[4], py[4];
  #pragma unroll
  for (int j=0;j<4;++j){
    pa[j] = *(const float4*)(Ap + (long)(32*j)*K);
    if (ADD2) py[j] = *(const float4*)(A2p + (long)(32*j)*K);
    pb[j] = *(const float4*)(Wp + (long)(32*j)*K);
  }

  for (int k0 = 0; k0 < K; k0 += 32){
    __syncthreads();
    #pragma unroll
    for (int j=0;j<4;++j){
      float4 v = pa[j];
      if (ADD2){ v.x+=py[j].x; v.y+=py[j].y; v.z+=py[j].z; v.w+=py[j].w; }
      stage_store(lsA, rA + 32*j, c4, v);
      stage_store(lsB, rA + 32*j, c4, pb[j]);
    }
    __syncthreads();
    if (k0 + 32 < K){
      #pragma unroll
      for (int j=0;j<4;++j){
        pa[j] = *(const float4*)(Ap + (k0+32) + (long)(32*j)*K);
        if (ADD2) py[j] = *(const float4*)(A2p + (k0+32) + (long)(32*j)*K);
        pb[j] = *(const float4*)(Wp + (k0+32) + (long)(32*j)*K);
      }
    }
    short8 af[4], bfr[4];
    #pragma unroll
    for (int mi=0;mi<4;++mi) af[mi]  = frag_load(lsA, wm*64 + mi*16 + rr, g);
    #pragma unroll
    for (int ni=0;ni<4;++ni) bfr[ni] = frag_load(lsB, wn*64 + ni*16 + rr, g);
    #pragma unroll
    for (int mi=0;mi<4;++mi)
      #pragma unroll
      for (int ni=0;ni<4;++ni)
        acc[mi][ni] = __builtin_amdgcn_mfma_f32_16x16x32_bf16(af[mi], bfr[ni], acc[mi][ni], 0, 0, 0);
  }
  const int cg = lane >> 4;
  #pragma unroll
  for (int ni=0;ni<4;++ni){
    long n = rowB0 + wn*64 + ni*16 + (lane & 15);
    float bv = bias[n];
    #pragma unroll
    for (int mi=0;mi<4;++mi){
      long m = rowA0 + wm*64 + mi*16 + cg*4;
      #pragma unroll
      for (int r2=0;r2<4;++r2){
        float v = acc[mi][ni][r2] + bv;
        if (RELU) v = fmaxf(v, 0.f);
        if (OUT_BF16) ((ushort_t*)Cout)[(m+r2)*N + n] = f2bf(v);
        else          ((float*)Cout)[(m+r2)*N + n] = v;
      }
    }
  }
}

// ---------- MFMA flash attention ----------
// QK: (8,1024,512) [q cols 0-255 (h*32+dh), k cols 256-511]; V: (8,1024,256)
// Per block: one (b,h), 128 q rows (wave w owns q rows w*32..w*32+31).
// S^T = mfma(K, Q)  -> lane holds 4 consecutive k at fixed q -> packed b64 P-writes.
// O^T = mfma(V^T, P) with P as [q][k] (B-operand layout), V^T staged transposed.
// Scores are tiny (std ~0.1) -> softmax without max subtraction is safe.
__global__ __launch_bounds__(256) void attn_mfma_kernel(const float* __restrict__ QK,
    const float* __restrict__ V, float* __restrict__ O){
  __shared__ ushort_t lsQ[4096];   // [128 q][32 dh]
  __shared__ ushort_t lsK[1024];   // [32 k][32 dh]
  __shared__ ushort_t lsVT[1024];  // [32 d][32 k]
  __shared__ ushort_t lsP[4096];   // [128 q][32 k]
  const int bh = blockIdx.y, b = bh >> 3, h = bh & 7;
  const int qt0 = blockIdx.x * 128;
  const int t = threadIdx.x, lane = t & 63, w = t >> 6;
  const int rr = lane & 15, g = lane >> 4;
  const float csc = 0.25506332f;   // log2(e)/sqrt(32)

  const float* qbase = QK + ((long)b*1024 + qt0)*512 + h*32;
  #pragma unroll
  for (int j=0;j<4;++j){
    int i = t + j*256; int r = i>>3, c4i = i&7;
    float4 v = *(const float4*)(qbase + (long)r*512 + c4i*4);
    stage_store(lsQ, r, c4i, v);
  }
  __syncthreads();
  short8 bq[2];
  bq[0] = frag_load(lsQ, w*32 + rr, g);
  bq[1] = frag_load(lsQ, w*32 + 16 + rr, g);

  floatx4 accO[2][2] = {};
  float rsum[2] = {0.f, 0.f};
  const float* kbase = QK + (long)b*1024*512 + 256 + h*32;
  const float* vbase = V  + (long)b*1024*256 + h*32;

  for (int kt = 0; kt < 1024; kt += 32){
    __syncthreads();
    { // stage K tile (32 x 32), natural layout
      int r = t >> 3, c4i = t & 7;
      float4 v = *(const float4*)(kbase + (long)(kt + r)*512 + c4i*4);
      stage_store(lsK, r, c4i, v);
    }
    { // stage V tile transposed -> lsVT[d][k]
      int kk = t >> 3, d4 = t & 7;
      float4 vv = *(const float4*)(vbase + (long)(kt + kk)*256 + d4*4);
      float vals[4] = {vv.x, vv.y, vv.z, vv.w};
      #pragma unroll
      for (int j=0;j<4;++j){
        int d = d4*4 + j;
        int cb = kk*2;
        int byte = d*64 + ((((cb>>4) ^ ((d>>1)&3)) << 4) | (cb & 15));
        *(ushort_t*)((char*)lsVT + byte) = f2bf(vals[j]);
      }
    }
    __syncthreads();
    floatx4 accS[2][2] = {};
    short8 ak0 = frag_load(lsK, rr, g);
    short8 ak1 = frag_load(lsK, 16 + rr, g);
    accS[0][0] = __builtin_amdgcn_mfma_f32_16x16x32_bf16(ak0, bq[0], accS[0][0], 0,0,0);
    accS[0][1] = __builtin_amdgcn_mfma_f32_16x16x32_bf16(ak0, bq[1], accS[0][1], 0,0,0);
    accS[1][0] = __builtin_amdgcn_mfma_f32_16x16x32_bf16(ak1, bq[0], accS[1][0], 0,0,0);
    accS[1][1] = __builtin_amdgcn_mfma_f32_16x16x32_bf16(ak1, bq[1], accS[1][1], 0,0,0);
    #pragma unroll
    for (int mi=0;mi<2;++mi){
      #pragma unroll
      for (int ni=0;ni<2;++ni){
        float p0 = exp2f(accS[mi][ni][0]*csc);
        float p1 = exp2f(accS[mi][ni][1]*csc);
        float p2 = exp2f(accS[mi][ni][2]*csc);
        float p3 = exp2f(accS[mi][ni][3]*csc);
        rsum[ni] += (p0+p1)+(p2+p3);
        int q   = w*32 + ni*16 + rr;
        int k0b = (mi*16 + g*4)*2;
        int byte = q*64 + ((((k0b>>4) ^ ((q>>1)&3)) << 4) | (k0b & 15));
        uint2 u; u.x = packbf2(p0,p1); u.y = packbf2(p2,p3);
        *(uint2*)((char*)lsP + byte) = u;
      }
    }
    short8 av0 = frag_load(lsVT, rr, g);
    short8 av1 = frag_load(lsVT, 16 + rr, g);
    short8 bp0 = frag_load(lsP, w*32 + rr, g);
    short8 bp1 = frag_load(lsP, w*32 + 16 + rr, g);
    accO[0][0] = __builtin_amdgcn_mfma_f32_16x16x32_bf16(av0, bp0, accO[0][0], 0,0,0);
    accO[0][1] = __builtin_amdgcn_mfma_f32_16x16x32_bf16(av0, bp1, accO[0][1], 0,0,0);
    accO[1][0] = __builtin_amdgcn_mfma_f32_16x16x32_bf16(av1, bp0, accO[1][0], 0,0,0);
    accO[1][1] = __builtin_amdgcn_mfma_f32_16x16x32_bf16(av1, bp1, accO[1][1], 0,0,0);
  }
  #pragma unroll
  for (int ni=0;ni<2;++ni){
    rsum[ni] += __shfl_xor(rsum[ni], 16);
    rsum[ni] += __shfl_xor(rsum[ni], 32);
    float inv = 1.f / rsum[ni];
    int q = qt0 + w*32 + ni*16 + rr;
    float* op = O + ((long)b*1024 + q)*256 + h*32;
    #pragma unroll
    for (int mi=0;mi<2;++mi){
      #pragma unroll
      for (int r2=0;r2<4;++r2){
        int d = mi*16 + g*4 + r2;
        op[d] = accO[mi][ni][r2] * inv;
      }
    }
  }
}

// ---------- multi-scale deformable attention sampling ----------
__global__ __launch_bounds__(256) void deform_kernel(const ushort_t* __restrict__ val,
    const float* __restrict__ offs, const float* __restrict__ awl,
    const float* __restrict__ refp, float* __restrict__ Out){
  int bq = blockIdx.x; int b = bq >> 10;
  int t = threadIdx.x; int h = t >> 5, d = t & 31;
  __shared__ float s_off[256], s_aw[128], s_ref[8];
  s_off[t] = offs[(long)bq*256 + t];
  if (t < 128) s_aw[t] = awl[(long)bq*128 + t];
  if (t < 8)   s_ref[t] = refp[(long)bq*8 + t];
  __syncthreads();
  float mx = -1e30f;
  #pragma unroll
  for (int i=0;i<16;++i) mx = fmaxf(mx, s_aw[h*16+i]);
  float p[16], sum = 0.f;
  #pragma unroll
  for (int i=0;i<16;++i){ p[i] = expf(s_aw[h*16+i] - mx); sum += p[i]; }
  float inv = 1.f/sum;
  const long vb = (long)b*21760*256 + h*32 + d;
  const int Ws[4] = {128,64,32,16};
  const int Hs[4] = {128,64,32,16};
  const int St[4] = {0,16384,20480,21504};
  float acc = 0.f;
  #pragma unroll
  for (int l=0;l<4;++l){
    const int Wl = Ws[l], Hl = Hs[l], st = St[l];
    float rx = s_ref[2*l], ry = s_ref[2*l+1];
    #pragma unroll
    for (int pp=0;pp<4;++pp){
      float ox = s_off[h*32 + l*8 + pp*2];
      float oy = s_off[h*32 + l*8 + pp*2 + 1];
      float x = rx*(float)Wl + ox - 0.5f;
      float y = ry*(float)Hl + oy - 0.5f;
      float xf = floorf(x), yf = floorf(y);
      int x0 = (int)xf, y0 = (int)yf;
      float tx = x - xf, ty = y - yf;
      float w00 = (1.f-tx)*(1.f-ty), w10 = tx*(1.f-ty);
      float w01 = (1.f-tx)*ty,       w11 = tx*ty;
      float sample = 0.f;
      if (x0 >= 0   && x0   < Wl && y0 >= 0   && y0   < Hl)
        sample += w00 * bf2f(val[vb + (long)(st + y0*Wl + x0)*256]);
      if (x0+1 >= 0 && x0+1 < Wl && y0 >= 0   && y0   < Hl)
        sample += w10 * bf2f(val[vb + (long)(st + y0*Wl + x0+1)*256]);
      if (x0 >= 0   && x0   < Wl && y0+1 >= 0 && y0+1 < Hl)
        sample += w01 * bf2f(val[vb + (long)(st + (y0+1)*Wl + x0)*256]);
      if (x0+1 >= 0 && x0+1 < Wl && y0+1 >= 0 && y0+1 < Hl)
        sample += w11 * bf2f(val[vb + (long)(st + (y0+1)*Wl + x0+1)*256]);
      acc += p[l*4+pp] * sample;
    }
  }
  Out[(long)bq*256 + t] = acc * inv;
}

// ---------------- host launcher ----------------
extern "C" void kernel_launch(void* const* d_in, const int* in_sizes, int n_in,
                              void* d_out, int out_size, void* d_ws, size_t ws_size,
                              hipStream_t stream){
  (void)in_sizes; (void)n_in; (void)out_size; (void)ws_size;
  const float* tgt   = (const float*)d_in[0];
  const float* qpos  = (const float*)d_in[1];
  const float* refp  = (const float*)d_in[2];
  const float* src   = (const float*)d_in[3];
  const float* w_in  = (const float*)d_in[4];
  const float* b_in  = (const float*)d_in[5];
  const float* w_out = (const float*)d_in[6];
  const float* b_out = (const float*)d_in[7];
  const float* ln1g  = (const float*)d_in[8];
  const float* ln1b  = (const float*)d_in[9];
  const float* ln2g  = (const float*)d_in[10];
  const float* ln2b  = (const float*)d_in[11];
  const float* ln3g  = (const float*)d_in[12];
  const float* ln3b  = (const float*)d_in[13];
  const float* w_val = (const float*)d_in[14];
  const float* b_val = (const float*)d_in[15];
  const float* w_off = (const float*)d_in[16];
  const float* b_off = (const float*)d_in[17];
  const float* w_attw= (const float*)d_in[18];
  const float* b_attw= (const float*)d_in[19];
  const float* w_oc  = (const float*)d_in[20];
  const float* b_oc  = (const float*)d_in[21];
  const float* w1    = (const float*)d_in[22];
  const float* b1    = (const float*)d_in[23];
  const float* w2    = (const float*)d_in[24];
  const float* b2    = (const float*)d_in[25];

  float* ws = (float*)d_ws;
  float* bufQK  = ws + 2097152;          // 4M floats (q|k proj)
  float* bufOff = ws + 2097152;          // reuse (after attn)
  float* bufAW  = ws + 4194304;          // reuse
  float* bufV   = ws + 6291456;          // 2M
  float* bufO   = ws + 8388608;          // 2M
  float* bufT2  = ws + 10485760;         // 2M
  float* bufTg1 = ws + 12582912;         // 2M
  float* bufTg2 = ws + 14680064;         // 2M
  ushort_t* bufVal = (ushort_t*)(ws + 16777216);  // bf16 (89MB)
  float* bufH   = ws + 16777216;         // reuse bufVal region (FFN hidden, 32MB)
  float* outF   = (float*)d_out;

  dim3 B256(256);
  // 1. q|k projection, A = tgt + query_pos fused (w_in rows 0..511)
  gemm_kernel<false,false,true><<<dim3(64,4), B256, 0, stream>>>(tgt, qpos, w_in, b_in, bufQK, 8192, 512, 256);
  // 2. v projection (w_in rows 512..767, input = tgt)
  gemm_kernel<false,false,false><<<dim3(64,2), B256, 0, stream>>>(tgt, nullptr, w_in + 512*256, b_in + 512, bufV, 8192, 256, 256);
  // 3. attention (MFMA flash)
  attn_mfma_kernel<<<dim3(8,64), B256, 0, stream>>>(bufQK, bufV, bufO);
  // 4. output projection
  gemm_kernel<false,false,false><<<dim3(64,2), B256, 0, stream>>>(bufO, nullptr, w_out, b_out, bufT2, 8192, 256, 256);
  // 5. tgt1 = LN2(tgt + t2)
  addln_kernel<<<dim3(2048), B256, 0, stream>>>(tgt, bufT2, ln2g, ln2b, bufTg1);
  // 6. value projection (bf16 out)
  gemm_kernel<false,true,false><<<dim3(1360,2), B256, 0, stream>>>(src, nullptr, w_val, b_val, bufVal, 174080, 256, 256);
  // 7. sampling offsets, A = tgt1 + query_pos fused
  gemm_kernel<false,false,true><<<dim3(64,2), B256, 0, stream>>>(bufTg1, qpos, w_off, b_off, bufOff, 8192, 256, 256);
  // 8. attention-weight logits, A = tgt1 + query_pos fused
  gemm_kernel<false,false,true><<<dim3(64,1), B256, 0, stream>>>(bufTg1, qpos, w_attw, b_attw, bufAW, 8192, 128, 256);
  // 9. deformable sampling
  deform_kernel<<<dim3(8192), B256, 0, stream>>>(bufVal, bufOff, bufAW, refp, bufO);
  // 10. output-context projection
  gemm_kernel<false,false,false><<<dim3(64,2), B256, 0, stream>>>(bufO, nullptr, w_oc, b_oc, bufT2, 8192, 256, 256);
  // 11. tgt2 = LN1(tgt1 + ca)
  addln_kernel<<<dim3(2048), B256, 0, stream>>>(bufTg1, bufT2, ln1g, ln1b, bufTg2);
  // 12. FFN up + relu
  gemm_kernel<true,false,false><<<dim3(64,8), B256, 0, stream>>>(bufTg2, nullptr, w1, b1, bufH, 8192, 1024, 256);
  // 13. FFN down
  gemm_kernel<false,false,false><<<dim3(64,2), B256, 0, stream>>>(bufH, nullptr, w2, b2, bufT2, 8192, 256, 1024);
  // 14. out = LN3(tgt2 + t2)
  addln_kernel<<<dim3(2048), B256, 0, stream>>>(bufTg2, bufT2, ln3g, ln3b, outF);
}